// Round 1
// baseline (622.214 us; speedup 1.0000x reference)
//
#include <hip/hip_runtime.h>
#include <cstdint>
#include <cstddef>

// ---------------------------------------------------------------------------
// feature_matching: corr(P=20, C=64) -> 4x (depthwise 3^3 + pointwise) blocks
// Shapes: rgb/depth (8,64,64,192) fp32
//   corr  -> (8,20,20,64,192)  [stored bf16 in ws @0,       78,643,200 B]
//   blk1  -> (8,20,20,64,192)  [stored bf16 in ws @78.6MB,  78,643,200 B]
//   blk2  -> (8,40,10,32,96)   [fp32 in ws @0   (corr dead), 39,321,600 B]
//   blk3  -> (8,40,10,32,96)   [fp32 in ws @78.6MB (b1 dead)]
//   blk4  -> (8,80,5,16,48)    fp32 -> d_out
// Peak ws usage: 157,286,400 bytes.
// ---------------------------------------------------------------------------

typedef unsigned short bf16_t;

static __device__ inline float b2f(bf16_t u) {
    union { float f; uint32_t i; } v; v.i = ((uint32_t)u) << 16; return v.f;
}
static __device__ inline bf16_t f2b(float f) {
    union { float f; uint32_t i; } v; v.f = f;
    uint32_t r = v.i + 0x7fffu + ((v.i >> 16) & 1u);  // round-nearest-even
    return (bf16_t)(r >> 16);
}

static __device__ inline float4 ld4(const float* p) { return *(const float4*)p; }
static __device__ inline float4 ld4(const bf16_t* p) {
    ushort4 u = *(const ushort4*)p;
    return make_float4(b2f(u.x), b2f(u.y), b2f(u.z), b2f(u.w));
}
static __device__ inline float ld1(const float* p) { return *p; }
static __device__ inline float ld1(const bf16_t* p) { return b2f(*p); }
static __device__ inline void st1(float* p, float v) { *p = v; }
static __device__ inline void st1(bf16_t* p, float v) { *p = f2b(v); }

// ---------------------------------------------------------------------------
// Correlation kernel.
// corr[b,di,dj,h,w] = sum_c rgb[b,c,h,w] * depth[b,c,h+di-10, w+dj-10] (0-pad)
// Grid: (2 W-halves, 64 h, 8 b). Block: 512 threads (480 active compute):
//   thread = (di = tid%20, wgroup = tid/20); each thread owns 4 adjacent
//   pixels w0..w0+3 and all 20 dj accumulators -> acc[4][20].
// LDS: depth tile [20 rows][117 float4-slots] (4-channel chunk). Pitch 117
//   (==5 mod 8) + di-fastest lane order => near conflict-free ds_read_b128.
// Each b128 read feeds up to 16 fmacs (4 px * 4 ch) -> register reuse.
// ---------------------------------------------------------------------------
__global__ __launch_bounds__(512) void corr_kernel(
        const float* __restrict__ rgb, const float* __restrict__ depth,
        bf16_t* __restrict__ out) {
    const int half = blockIdx.x;   // 0..1 -> W offset 0 / 96
    const int h    = blockIdx.y;   // 0..63
    const int b    = blockIdx.z;   // 0..7
    const int tid  = threadIdx.x;
    const int wbase = half * 96;

    __shared__ float4 Sd[20 * 117];  // [row][col] cols 0..114 valid
    __shared__ float4 Rr[96];        // rgb row, 4 channels per slot

    const int di  = tid % 20;
    const int wg  = tid / 20;        // 0..23 for tid<480
    const int w0l = wg * 4;

    float acc[4][20];
#pragma unroll
    for (int p = 0; p < 4; ++p)
#pragma unroll
        for (int j = 0; j < 20; ++j) acc[p][j] = 0.f;

    for (int c0 = 0; c0 < 64; c0 += 4) {
        // ---- stage depth: 20 rows x 115 cols, 4 channels packed per float4
        for (int i = tid; i < 20 * 115; i += 512) {
            const int row = i / 115;
            const int col = i - row * 115;
            const int gr = h + row - 10;
            const int gc = wbase + col - 10;
            float4 v = make_float4(0.f, 0.f, 0.f, 0.f);
            if (gr >= 0 && gr < 64 && gc >= 0 && gc < 192) {
                const float* gp = depth + ((size_t)(b * 64 + c0) * 64 + gr) * 192 + gc;
                v.x = gp[0]; v.y = gp[12288]; v.z = gp[24576]; v.w = gp[36864];
            }
            Sd[row * 117 + col] = v;
        }
        // ---- stage rgb row (96 px, 4 channels)
        for (int i = tid; i < 96; i += 512) {
            const float* gp = rgb + ((size_t)(b * 64 + c0) * 64 + h) * 192 + wbase + i;
            Rr[i] = make_float4(gp[0], gp[12288], gp[24576], gp[36864]);
        }
        __syncthreads();

        if (tid < 480) {
            float4 rr[4];
#pragma unroll
            for (int p = 0; p < 4; ++p) rr[p] = Rr[w0l + p];
#pragma unroll
            for (int ct = 0; ct < 23; ++ct) {
                const float4 dv = Sd[di * 117 + w0l + ct];
#pragma unroll
                for (int p = 0; p < 4; ++p) {
                    const int dj = ct - p;   // compile-time after unroll
                    if (dj >= 0 && dj < 20) {
                        acc[p][dj] = fmaf(rr[p].x, dv.x, acc[p][dj]);
                        acc[p][dj] = fmaf(rr[p].y, dv.y, acc[p][dj]);
                        acc[p][dj] = fmaf(rr[p].z, dv.z, acc[p][dj]);
                        acc[p][dj] = fmaf(rr[p].w, dv.w, acc[p][dj]);
                    }
                }
            }
        }
        __syncthreads();
    }

    if (tid < 480) {
#pragma unroll
        for (int dj = 0; dj < 20; ++dj) {
            ushort4 o;
            o.x = f2b(acc[0][dj]); o.y = f2b(acc[1][dj]);
            o.z = f2b(acc[2][dj]); o.w = f2b(acc[3][dj]);
            *(ushort4*)&out[(((size_t)(b * 20 + di) * 20 + dj) * 64 + h) * 192 + wbase + w0l] = o;
        }
    }
}

// ---------------------------------------------------------------------------
// Fused depthwise-3^3 (+bias+leaky) -> pointwise 1x1x1 (+bias+leaky) block.
// Output tile per block: (d fixed, 4 h, 48 w) for ALL COUT channels.
// Phase 1: per (ci, w-quad) compute 4h x 4w depthwise outputs with a sliding
//   float4 register window (A/B/C loads) -> LDS tile sT[CIN][4][48].
// Phase 2: 192 threads (one per position), dw activations from LDS, pw
//   weights via wave-uniform global loads (scalarized to s_load).
// ---------------------------------------------------------------------------
template<int CIN, int COUT, int S, int DIN, int HIN, int WIN,
         int DO, int HO, int WO, typename TIN, typename TOUT>
__global__ __launch_bounds__(256) void fused_block(
        const TIN* __restrict__ x,
        const float* __restrict__ dw_w, const float* __restrict__ dw_b,
        const float* __restrict__ pw_w, const float* __restrict__ pw_b,
        TOUT* __restrict__ y) {
    static_assert(WO % 48 == 0 && HO % 4 == 0, "tile divisibility");
    constexpr int WT = WO / 48;
    const int wt = blockIdx.x % WT;
    const int ht = blockIdx.x / WT;
    const int d  = blockIdx.y;
    const int b  = blockIdx.z;
    const int tid = threadIdx.x;
    const int h0 = ht * 4;
    const int wbase = wt * 48;

    __shared__ float sDW[CIN * 27];
    __shared__ float sDB[CIN];
    __shared__ float sT[CIN][4][48];

    for (int i = tid; i < CIN * 27; i += 256) sDW[i] = dw_w[i];
    for (int i = tid; i < CIN; i += 256) sDB[i] = dw_b[i];
    __syncthreads();

    // ---------------- phase 1: depthwise ----------------
    for (int idx = tid; idx < CIN * 12; idx += 256) {
        const int ci = idx / 12;
        const int wq = idx - ci * 12;
        const int w0g = wbase + wq * 4;          // output-w base (global)

        float K[27];
#pragma unroll
        for (int k = 0; k < 27; ++k) K[k] = sDW[ci * 27 + k];

        float acc[4][4];
#pragma unroll
        for (int a = 0; a < 4; ++a)
#pragma unroll
            for (int c = 0; c < 4; ++c) acc[a][c] = 0.f;

        const TIN* plane0 = x + (size_t)(b * CIN + ci) * DIN * HIN * WIN;
#pragma unroll
        for (int kd = 0; kd < 3; ++kd) {
            const int din = d * S + kd - 1;
            if (din < 0 || din >= DIN) continue;       // block-uniform
            const TIN* pl = plane0 + (size_t)din * HIN * WIN;
#pragma unroll
            for (int r = 0; r < 3 * S + 3; ++r) {
                const int hin = h0 * S - 1 + r;
                if (hin < 0 || hin >= HIN) continue;   // block-uniform
                const TIN* rowp = pl + (size_t)hin * WIN + w0g * S;
                // window win[j] = x[w0g*S - 1 + j], j = 0 .. 3S+2
                float win[3 * S + 3];
                float4 Av = make_float4(0.f, 0.f, 0.f, 0.f);
                if (w0g > 0) Av = ld4(rowp - 4);
                const float4 Bv = ld4(rowp);
                win[0] = Av.w; win[1] = Bv.x; win[2] = Bv.y; win[3] = Bv.z; win[4] = Bv.w;
                if constexpr (S == 1) {
                    win[5] = (w0g + 4 < WIN) ? ld1(rowp + 4) : 0.f;
                } else {
                    const float4 Cv = ld4(rowp + 4);   // always in-bounds for S=2
                    win[5] = Cv.x; win[6] = Cv.y; win[7] = Cv.z; win[8] = Cv.w;
                }
#pragma unroll
                for (int hh = 0; hh < 4; ++hh) {
                    const int kh = r - hh * S;         // compile-time
                    if (kh < 0 || kh > 2) continue;
#pragma unroll
                    for (int ww = 0; ww < 4; ++ww) {
#pragma unroll
                        for (int kw = 0; kw < 3; ++kw)
                            acc[hh][ww] = fmaf(win[ww * S + kw],
                                               K[kd * 9 + kh * 3 + kw], acc[hh][ww]);
                    }
                }
            }
        }
        const float bia = sDB[ci];
#pragma unroll
        for (int hh = 0; hh < 4; ++hh) {
            float t0 = acc[hh][0] + bia, t1 = acc[hh][1] + bia;
            float t2 = acc[hh][2] + bia, t3 = acc[hh][3] + bia;
            float4 o;
            o.x = fmaxf(t0, 0.1f * t0); o.y = fmaxf(t1, 0.1f * t1);
            o.z = fmaxf(t2, 0.1f * t2); o.w = fmaxf(t3, 0.1f * t3);
            *(float4*)&sT[ci][hh][wq * 4] = o;
        }
    }
    __syncthreads();

    // ---------------- phase 2: pointwise ----------------
    if (tid < 192) {
        const int hh = tid / 48;
        const int ww = tid - hh * 48;
        float L[CIN];
#pragma unroll
        for (int ci = 0; ci < CIN; ++ci) L[ci] = sT[ci][hh][ww];
        const size_t planeSz = (size_t)DO * HO * WO;
        TOUT* yb = y + (size_t)b * COUT * planeSz + (size_t)d * HO * WO
                     + (size_t)(h0 + hh) * WO + (wbase + ww);
        for (int co = 0; co < COUT; ++co) {
            float s = pw_b[co];                      // uniform -> s_load
#pragma unroll
            for (int ci = 0; ci < CIN; ++ci)
                s = fmaf(pw_w[co * CIN + ci], L[ci], s);  // uniform weights
            st1(yb + (size_t)co * planeSz, fmaxf(s, 0.1f * s));
        }
    }
}

// ---------------------------------------------------------------------------
extern "C" void kernel_launch(void* const* d_in, const int* in_sizes, int n_in,
                              void* d_out, int out_size, void* d_ws, size_t ws_size,
                              hipStream_t stream) {
    const float* rgb  = (const float*)d_in[0];
    const float* dep  = (const float*)d_in[1];
    const float* dw1w = (const float*)d_in[2];
    const float* dw1b = (const float*)d_in[3];
    const float* pw1w = (const float*)d_in[4];
    const float* pw1b = (const float*)d_in[5];
    const float* dw2w = (const float*)d_in[6];
    const float* dw2b = (const float*)d_in[7];
    const float* pw2w = (const float*)d_in[8];
    const float* pw2b = (const float*)d_in[9];
    const float* dw3w = (const float*)d_in[10];
    const float* dw3b = (const float*)d_in[11];
    const float* pw3w = (const float*)d_in[12];
    const float* pw3b = (const float*)d_in[13];
    const float* dw4w = (const float*)d_in[14];
    const float* dw4b = (const float*)d_in[15];
    const float* pw4w = (const float*)d_in[16];
    const float* pw4b = (const float*)d_in[17];

    const size_t HALF = 78643200;  // 39,321,600 bf16 elements
    bf16_t* corrO = (bf16_t*)d_ws;
    bf16_t* b1o   = (bf16_t*)((char*)d_ws + HALF);
    float*  b2o   = (float*)d_ws;                     // corr region (dead)
    float*  b3o   = (float*)((char*)d_ws + HALF);     // b1 region (dead)
    float*  outp  = (float*)d_out;

    corr_kernel<<<dim3(2, 64, 8), 512, 0, stream>>>(rgb, dep, corrO);

    fused_block<20, 20, 1, 20, 64, 192, 20, 64, 192, bf16_t, bf16_t>
        <<<dim3(64, 20, 8), 256, 0, stream>>>(corrO, dw1w, dw1b, pw1w, pw1b, b1o);

    fused_block<20, 40, 2, 20, 64, 192, 10, 32, 96, bf16_t, float>
        <<<dim3(16, 10, 8), 256, 0, stream>>>(b1o, dw2w, dw2b, pw2w, pw2b, b2o);

    fused_block<40, 40, 1, 10, 32, 96, 10, 32, 96, float, float>
        <<<dim3(16, 10, 8), 256, 0, stream>>>(b2o, dw3w, dw3b, pw3w, pw3b, b3o);

    fused_block<40, 80, 2, 10, 32, 96, 5, 16, 48, float, float>
        <<<dim3(4, 5, 8), 256, 0, stream>>>(b3o, dw4w, dw4b, pw4w, pw4b, outp);
}

// Round 2
// 521.338 us; speedup vs baseline: 1.1935x; 1.1935x over previous
//
#include <hip/hip_runtime.h>
#include <cstdint>
#include <cstddef>

// ---------------------------------------------------------------------------
// feature_matching: corr(P=20, C=64) -> 4x (depthwise 3^3 + pointwise) blocks
//
// R2: correlation via MFMA. Prepass transposes rgb/depth (b,c,h,w) f32 ->
// (b,h,w,c) bf16 so MFMA fragments load as one dwordx4 per lane. Per
// (b,h,di) block: Z[w,u] = sum_c rgb[c,w]*dep[c,u] computed on 16x16 tiles
// (3 u-tiles per w-tile cover the |u-w|<=10..9 band), scattered to LDS in
// (w,dj) coordinates, then stored coalesced as bf16.
//
// ws layout (peak 157,286,400 B):
//   [0,        78.6MB): corrO (bf16)        -> later b2o (fp32, 39.3MB)
//   [78.6MB,  157.3MB): rgbT+depT (bf16)    -> later b1o (bf16, 78.6MB)
//                                           -> later b3o (fp32, 39.3MB)
// ---------------------------------------------------------------------------

typedef unsigned short bf16_t;
typedef __attribute__((ext_vector_type(8))) short short8;
typedef __attribute__((ext_vector_type(4))) float f32x4;

static __device__ inline float b2f(bf16_t u) {
    union { float f; uint32_t i; } v; v.i = ((uint32_t)u) << 16; return v.f;
}
static __device__ inline bf16_t f2b(float f) {
    union { float f; uint32_t i; } v; v.f = f;
    uint32_t r = v.i + 0x7fffu + ((v.i >> 16) & 1u);  // round-nearest-even
    return (bf16_t)(r >> 16);
}

static __device__ inline float4 ld4(const float* p) { return *(const float4*)p; }
static __device__ inline float4 ld4(const bf16_t* p) {
    ushort4 u = *(const ushort4*)p;
    return make_float4(b2f(u.x), b2f(u.y), b2f(u.z), b2f(u.w));
}
static __device__ inline float ld1(const float* p) { return *p; }
static __device__ inline float ld1(const bf16_t* p) { return b2f(*p); }
static __device__ inline void st1(float* p, float v) { *p = v; }
static __device__ inline void st1(bf16_t* p, float v) { *p = f2b(v); }

// ---------------------------------------------------------------------------
// Prepass: (b,c,h,w) fp32 -> (b,h,w,c) bf16, LDS tile transpose per (b,h).
// blockIdx.x = b*64+h, blockIdx.y = {0: rgb, 1: depth}.
// ---------------------------------------------------------------------------
__global__ __launch_bounds__(256) void transpose_bf16(
        const float* __restrict__ rgb, const float* __restrict__ dep,
        bf16_t* __restrict__ rgbT, bf16_t* __restrict__ depT) {
    const int bh = blockIdx.x;
    const float* src = blockIdx.y ? dep : rgb;
    bf16_t* dst = blockIdx.y ? depT : rgbT;
    const int tid = threadIdx.x;
    const int b = bh >> 6, h = bh & 63;

    __shared__ bf16_t S[64 * 194];

    const float* srcb = src + (size_t)b * 786432 + (size_t)h * 192;
#pragma unroll
    for (int it = 0; it < 12; ++it) {
        const int idx = it * 256 + tid;      // 3072 = 64c x 48 float4
        const int c = idx / 48, w4 = idx - c * 48;
        const float4 v = *(const float4*)(srcb + (size_t)c * 12288 + 4 * w4);
        bf16_t* sp = &S[c * 194 + 4 * w4];
        sp[0] = f2b(v.x); sp[1] = f2b(v.y); sp[2] = f2b(v.z); sp[3] = f2b(v.w);
    }
    __syncthreads();
    bf16_t* dstb = dst + (size_t)bh * 192 * 64;
#pragma unroll
    for (int it = 0; it < 12; ++it) {
        const int idx = it * 256 + tid;      // 3072 = 192w x 16 c4
        const int w = idx >> 4, c4 = idx & 15;
        ushort4 o;
        o.x = S[(4 * c4 + 0) * 194 + w];
        o.y = S[(4 * c4 + 1) * 194 + w];
        o.z = S[(4 * c4 + 2) * 194 + w];
        o.w = S[(4 * c4 + 3) * 194 + w];
        *(ushort4*)(dstb + (size_t)w * 64 + 4 * c4) = o;
    }
}

// ---------------------------------------------------------------------------
// MFMA correlation. Grid (di=20, h=64, b=8), 256 threads (4 waves).
// Wave owns 48 w (3 w-tiles of 16). Per w-tile: A-frag = rgbT row (w x c),
// 3 u-tiles of B from depT row hd; Z band via mfma_f32_16x16x32_bf16,
// scattered to LDS Dall[(w,dj)] with +w>>2 swizzle, stored ushort4/dj-row.
// corr[dj,w] = Z[w, u=w+dj-10]; dj = 16*ut + n - 4q - reg - 6.
// ---------------------------------------------------------------------------
__global__ __launch_bounds__(256) void corr_mfma(
        const bf16_t* __restrict__ rgbT, const bf16_t* __restrict__ depT,
        bf16_t* __restrict__ out) {
    const int di = blockIdx.x, h = blockIdx.y, b = blockIdx.z;
    const int tid = threadIdx.x;
    const int hd = h + di - 10;
    bf16_t* outb = out + ((size_t)((b * 20 + di) * 20) * 64 + h) * 192;

    if (hd < 0 || hd >= 64) {            // depth row fully in zero-pad
#pragma unroll
        for (int it = 0; it < 4; ++it) {
            const int idx = it * 256 + tid;
            if (idx < 960) {
                const int dj = idx / 48, w4 = idx - dj * 48;
                *(ushort4*)(outb + (size_t)dj * 12288 + 4 * w4) =
                    make_ushort4(0, 0, 0, 0);
            }
        }
        return;
    }

    __shared__ float Dall[4080];         // addr = w*21 + (w>>2) + dj
    const int lane = tid & 63, wave = tid >> 6;
    const int n = lane & 15, q = lane >> 4;

    const bf16_t* Abase = rgbT + (size_t)(b * 64 + h) * 192 * 64;
    const bf16_t* Bbase = depT + (size_t)(b * 64 + hd) * 192 * 64;

#pragma unroll
    for (int t = 0; t < 3; ++t) {
        const int w0 = wave * 48 + t * 16;
        const short8* Ap = (const short8*)(Abase + (size_t)(w0 + n) * 64 + q * 8);
        const short8 a0 = Ap[0];         // c = q*8 .. q*8+7
        const short8 a1 = Ap[4];         // c += 32
        f32x4 acc[3];
#pragma unroll
        for (int ut = 0; ut < 3; ++ut) {
            acc[ut].x = 0.f; acc[ut].y = 0.f; acc[ut].z = 0.f; acc[ut].w = 0.f;
        }
#pragma unroll
        for (int ut = 0; ut < 3; ++ut) {
            const int u0 = w0 + (ut - 1) * 16;
            if (u0 >= 0 && u0 <= 176) {  // wave-uniform; OOB tile stays 0
                const short8* Bp = (const short8*)(Bbase + (size_t)(u0 + n) * 64 + q * 8);
                acc[ut] = __builtin_amdgcn_mfma_f32_16x16x32_bf16(a0, Bp[0], acc[ut], 0, 0, 0);
                acc[ut] = __builtin_amdgcn_mfma_f32_16x16x32_bf16(a1, Bp[4], acc[ut], 0, 0, 0);
            }
        }
        // scatter band -> (w, dj) coordinates
#pragma unroll
        for (int ut = 0; ut < 3; ++ut) {
#pragma unroll
            for (int r = 0; r < 4; ++r) {
                const int dj = 16 * ut + n - 4 * q - r - 6;
                const int w = w0 + 4 * q + r;
                if (dj >= 0 && dj < 20)
                    Dall[w * 21 + (w >> 2) + dj] = acc[ut][r];
            }
        }
    }
    __syncthreads();
#pragma unroll
    for (int it = 0; it < 4; ++it) {
        const int idx = it * 256 + tid;
        if (idx < 960) {
            const int dj = idx / 48, w4 = idx - dj * 48;
            const int base = 85 * w4 + dj;   // (4*w4+j)*21 + w4 + dj
            ushort4 o;
            o.x = f2b(Dall[base]);
            o.y = f2b(Dall[base + 21]);
            o.z = f2b(Dall[base + 42]);
            o.w = f2b(Dall[base + 63]);
            *(ushort4*)(outb + (size_t)dj * 12288 + 4 * w4) = o;
        }
    }
}

// ---------------------------------------------------------------------------
// Fused depthwise-3^3 (+bias+leaky) -> pointwise 1x1x1 (+bias+leaky) block.
// (unchanged from R1 — counters for these arrive next round)
// ---------------------------------------------------------------------------
template<int CIN, int COUT, int S, int DIN, int HIN, int WIN,
         int DO, int HO, int WO, typename TIN, typename TOUT>
__global__ __launch_bounds__(256) void fused_block(
        const TIN* __restrict__ x,
        const float* __restrict__ dw_w, const float* __restrict__ dw_b,
        const float* __restrict__ pw_w, const float* __restrict__ pw_b,
        TOUT* __restrict__ y) {
    static_assert(WO % 48 == 0 && HO % 4 == 0, "tile divisibility");
    constexpr int WT = WO / 48;
    const int wt = blockIdx.x % WT;
    const int ht = blockIdx.x / WT;
    const int d  = blockIdx.y;
    const int b  = blockIdx.z;
    const int tid = threadIdx.x;
    const int h0 = ht * 4;
    const int wbase = wt * 48;

    __shared__ float sDW[CIN * 27];
    __shared__ float sDB[CIN];
    __shared__ float sT[CIN][4][48];

    for (int i = tid; i < CIN * 27; i += 256) sDW[i] = dw_w[i];
    for (int i = tid; i < CIN; i += 256) sDB[i] = dw_b[i];
    __syncthreads();

    // ---------------- phase 1: depthwise ----------------
    for (int idx = tid; idx < CIN * 12; idx += 256) {
        const int ci = idx / 12;
        const int wq = idx - ci * 12;
        const int w0g = wbase + wq * 4;

        float K[27];
#pragma unroll
        for (int k = 0; k < 27; ++k) K[k] = sDW[ci * 27 + k];

        float acc[4][4];
#pragma unroll
        for (int a = 0; a < 4; ++a)
#pragma unroll
            for (int c = 0; c < 4; ++c) acc[a][c] = 0.f;

        const TIN* plane0 = x + (size_t)(b * CIN + ci) * DIN * HIN * WIN;
#pragma unroll
        for (int kd = 0; kd < 3; ++kd) {
            const int din = d * S + kd - 1;
            if (din < 0 || din >= DIN) continue;       // block-uniform
            const TIN* pl = plane0 + (size_t)din * HIN * WIN;
#pragma unroll
            for (int r = 0; r < 3 * S + 3; ++r) {
                const int hin = h0 * S - 1 + r;
                if (hin < 0 || hin >= HIN) continue;   // block-uniform
                const TIN* rowp = pl + (size_t)hin * WIN + w0g * S;
                float win[3 * S + 3];
                float4 Av = make_float4(0.f, 0.f, 0.f, 0.f);
                if (w0g > 0) Av = ld4(rowp - 4);
                const float4 Bv = ld4(rowp);
                win[0] = Av.w; win[1] = Bv.x; win[2] = Bv.y; win[3] = Bv.z; win[4] = Bv.w;
                if constexpr (S == 1) {
                    win[5] = (w0g + 4 < WIN) ? ld1(rowp + 4) : 0.f;
                } else {
                    const float4 Cv = ld4(rowp + 4);
                    win[5] = Cv.x; win[6] = Cv.y; win[7] = Cv.z; win[8] = Cv.w;
                }
#pragma unroll
                for (int hh = 0; hh < 4; ++hh) {
                    const int kh = r - hh * S;
                    if (kh < 0 || kh > 2) continue;
#pragma unroll
                    for (int ww = 0; ww < 4; ++ww) {
#pragma unroll
                        for (int kw = 0; kw < 3; ++kw)
                            acc[hh][ww] = fmaf(win[ww * S + kw],
                                               K[kd * 9 + kh * 3 + kw], acc[hh][ww]);
                    }
                }
            }
        }
        const float bia = sDB[ci];
#pragma unroll
        for (int hh = 0; hh < 4; ++hh) {
            float t0 = acc[hh][0] + bia, t1 = acc[hh][1] + bia;
            float t2 = acc[hh][2] + bia, t3 = acc[hh][3] + bia;
            float4 o;
            o.x = fmaxf(t0, 0.1f * t0); o.y = fmaxf(t1, 0.1f * t1);
            o.z = fmaxf(t2, 0.1f * t2); o.w = fmaxf(t3, 0.1f * t3);
            *(float4*)&sT[ci][hh][wq * 4] = o;
        }
    }
    __syncthreads();

    // ---------------- phase 2: pointwise ----------------
    if (tid < 192) {
        const int hh = tid / 48;
        const int ww = tid - hh * 48;
        float L[CIN];
#pragma unroll
        for (int ci = 0; ci < CIN; ++ci) L[ci] = sT[ci][hh][ww];
        const size_t planeSz = (size_t)DO * HO * WO;
        TOUT* yb = y + (size_t)b * COUT * planeSz + (size_t)d * HO * WO
                     + (size_t)(h0 + hh) * WO + (wbase + ww);
        for (int co = 0; co < COUT; ++co) {
            float s = pw_b[co];
#pragma unroll
            for (int ci = 0; ci < CIN; ++ci)
                s = fmaf(pw_w[co * CIN + ci], L[ci], s);
            st1(yb + (size_t)co * planeSz, fmaxf(s, 0.1f * s));
        }
    }
}

// ---------------------------------------------------------------------------
extern "C" void kernel_launch(void* const* d_in, const int* in_sizes, int n_in,
                              void* d_out, int out_size, void* d_ws, size_t ws_size,
                              hipStream_t stream) {
    const float* rgb  = (const float*)d_in[0];
    const float* dep  = (const float*)d_in[1];
    const float* dw1w = (const float*)d_in[2];
    const float* dw1b = (const float*)d_in[3];
    const float* pw1w = (const float*)d_in[4];
    const float* pw1b = (const float*)d_in[5];
    const float* dw2w = (const float*)d_in[6];
    const float* dw2b = (const float*)d_in[7];
    const float* pw2w = (const float*)d_in[8];
    const float* pw2b = (const float*)d_in[9];
    const float* dw3w = (const float*)d_in[10];
    const float* dw3b = (const float*)d_in[11];
    const float* pw3w = (const float*)d_in[12];
    const float* pw3b = (const float*)d_in[13];
    const float* dw4w = (const float*)d_in[14];
    const float* dw4b = (const float*)d_in[15];
    const float* pw4w = (const float*)d_in[16];
    const float* pw4b = (const float*)d_in[17];

    const size_t HALF = 78643200;
    bf16_t* corrO = (bf16_t*)d_ws;
    bf16_t* rgbT  = (bf16_t*)((char*)d_ws + HALF);
    bf16_t* depT  = (bf16_t*)((char*)d_ws + HALF + 12582912);
    bf16_t* b1o   = (bf16_t*)((char*)d_ws + HALF);   // rgbT/depT dead by then
    float*  b2o   = (float*)d_ws;                    // corrO dead by then
    float*  b3o   = (float*)((char*)d_ws + HALF);    // b1o dead by then
    float*  outp  = (float*)d_out;

    transpose_bf16<<<dim3(512, 2), 256, 0, stream>>>(rgb, dep, rgbT, depT);

    corr_mfma<<<dim3(20, 64, 8), 256, 0, stream>>>(rgbT, depT, corrO);

    fused_block<20, 20, 1, 20, 64, 192, 20, 64, 192, bf16_t, bf16_t>
        <<<dim3(64, 20, 8), 256, 0, stream>>>(corrO, dw1w, dw1b, pw1w, pw1b, b1o);

    fused_block<20, 40, 2, 20, 64, 192, 10, 32, 96, bf16_t, float>
        <<<dim3(16, 10, 8), 256, 0, stream>>>(b1o, dw2w, dw2b, pw2w, pw2b, b2o);

    fused_block<40, 40, 1, 10, 32, 96, 10, 32, 96, float, float>
        <<<dim3(16, 10, 8), 256, 0, stream>>>(b2o, dw3w, dw3b, pw3w, pw3b, b3o);

    fused_block<40, 80, 2, 10, 32, 96, 5, 16, 48, float, float>
        <<<dim3(4, 5, 8), 256, 0, stream>>>(b3o, dw4w, dw4b, pw4w, pw4b, outp);
}